// Round 1
// baseline (447.046 us; speedup 1.0000x reference)
//
#include <hip/hip_runtime.h>

#define NB 8
#define NM 8192
#define NE 2048
#define ND 64

constexpr int K1_ROWS = 32;           // rows per block in K1
constexpr int K1_NBLK = NM / K1_ROWS; // 256 row-blocks per batch
constexpr int K4_ROWS = 64;           // rows per block in K4
constexpr int K4_NBLK = NM / K4_ROWS; // 128

// K1: agg[b,m,d] = sum_e inc[b,m,e] * ef[b,e,d]  (inc is exactly 0/1)
// fused: scores row = agg_row @ Wa^T, online-softmax partials per (block, d)
__global__ __launch_bounds__(256) void k1_agg_partial(
    const float* __restrict__ inc,   // [B][M][E]
    const float* __restrict__ ef,    // [B][E][D]
    const float* __restrict__ Wa,    // [D][D] (out,in)
    float* __restrict__ agg,         // [B][M][D]
    float* __restrict__ pmax,        // [B][K1_NBLK][D]
    float* __restrict__ psum)        // [B][K1_NBLK][D]
{
    __shared__ float WaT[ND * ND];   // WaT[d*64+o] = Wa[o*64+d]
    __shared__ float rowbuf[4][ND];
    __shared__ float smax[4][ND];
    __shared__ float ssum[4][ND];

    const int tid  = threadIdx.x;
    const int lane = tid & 63;
    const int wave = tid >> 6;
    const int blk  = blockIdx.x % K1_NBLK;
    const int b    = blockIdx.x / K1_NBLK;

    for (int i = tid; i < ND * ND; i += 256) {
        int o = i >> 6, d = i & 63;
        WaT[d * ND + o] = Wa[i];
    }
    __syncthreads();

    const float* efb = ef + (size_t)b * (NE * ND);

    float runmax = -INFINITY, runsum = 0.f;

    for (int r = 0; r < K1_ROWS / 4; ++r) {
        const int m = blk * K1_ROWS + r * 4 + wave;
        const float* incRow = inc + ((size_t)b * NM + m) * NE;
        float acc = 0.f;
        #pragma unroll
        for (int e0 = 0; e0 < NE; e0 += 256) {
            float4 v = *reinterpret_cast<const float4*>(incRow + e0 + lane * 4);
            unsigned long long m0 = __ballot(v.x != 0.f);
            unsigned long long m1 = __ballot(v.y != 0.f);
            unsigned long long m2 = __ballot(v.z != 0.f);
            unsigned long long m3 = __ballot(v.w != 0.f);
            while (m0) { int j = __builtin_ctzll(m0); m0 &= m0 - 1; acc += efb[(size_t)(e0 + j * 4 + 0) * ND + lane]; }
            while (m1) { int j = __builtin_ctzll(m1); m1 &= m1 - 1; acc += efb[(size_t)(e0 + j * 4 + 1) * ND + lane]; }
            while (m2) { int j = __builtin_ctzll(m2); m2 &= m2 - 1; acc += efb[(size_t)(e0 + j * 4 + 2) * ND + lane]; }
            while (m3) { int j = __builtin_ctzll(m3); m3 &= m3 - 1; acc += efb[(size_t)(e0 + j * 4 + 3) * ND + lane]; }
        }
        agg[((size_t)b * NM + m) * ND + lane] = acc;

        // scores row: s[o] = sum_d acc[d] * Wa[o][d]  (wave-private LDS, no barrier needed)
        rowbuf[wave][lane] = acc;
        float s = 0.f;
        #pragma unroll
        for (int d = 0; d < ND; ++d)
            s = fmaf(rowbuf[wave][d], WaT[d * ND + lane], s);

        float nm = fmaxf(runmax, s);
        runsum = runsum * __expf(runmax - nm) + __expf(s - nm);
        runmax = nm;
    }

    smax[wave][lane] = runmax;
    ssum[wave][lane] = runsum;
    __syncthreads();
    if (wave == 0) {
        float gm = smax[0][lane], gs = ssum[0][lane];
        for (int w = 1; w < 4; ++w) {
            float wm = smax[w][lane], ws = ssum[w][lane];
            float nm = fmaxf(gm, wm);
            gs = gs * __expf(gm - nm) + ws * __expf(wm - nm);
            gm = nm;
        }
        pmax[((size_t)b * K1_NBLK + blk) * ND + lane] = gm;
        psum[((size_t)b * K1_NBLK + blk) * ND + lane] = gs;
    }
}

// K3: combine per-block partials into per-(b,d) global (max, sum)
__global__ __launch_bounds__(256) void k3_combine(
    const float* __restrict__ pmax, const float* __restrict__ psum,
    float* __restrict__ gmaxv, float* __restrict__ gsumv)
{
    __shared__ float smax[4][ND], ssum[4][ND];
    const int b = blockIdx.x, d = threadIdx.x & 63, c = threadIdx.x >> 6;
    float gm = -INFINITY, gs = 0.f;
    for (int i = c; i < K1_NBLK; i += 4) {
        float wm = pmax[((size_t)b * K1_NBLK + i) * ND + d];
        float ws = psum[((size_t)b * K1_NBLK + i) * ND + d];
        float nm = fmaxf(gm, wm);
        gs = gs * __expf(gm - nm) + ws * __expf(wm - nm);
        gm = nm;
    }
    smax[c][d] = gm; ssum[c][d] = gs;
    __syncthreads();
    if (c == 0) {
        for (int w = 1; w < 4; ++w) {
            float wm = smax[w][d], ws = ssum[w][d];
            float nm = fmaxf(gm, wm);
            gs = gs * __expf(gm - nm) + ws * __expf(wm - nm);
            gm = nm;
        }
        gmaxv[b * ND + d] = gm;
        gsumv[b * ND + d] = gs;
    }
}

// K4: recompute scores, attn = softmax, weighted = agg*attn, @Wp^T, blend
__global__ __launch_bounds__(256) void k4_final(
    const float* __restrict__ agg, const float* __restrict__ Wa,
    const float* __restrict__ Wp, const float* __restrict__ prev,
    const float* __restrict__ gmaxv, const float* __restrict__ gsumv,
    const float* __restrict__ alpha_p, float* __restrict__ out)
{
    __shared__ float WaT[ND * ND], WpT[ND * ND];
    __shared__ float rowA[4][ND], rowW[4][ND];
    const int tid = threadIdx.x, lane = tid & 63, wave = tid >> 6;
    const int b = blockIdx.x / K4_NBLK, blk = blockIdx.x % K4_NBLK;

    for (int i = tid; i < ND * ND; i += 256) {
        int o = i >> 6, d = i & 63;
        WaT[d * ND + o] = Wa[i];
        WpT[d * ND + o] = Wp[i];
    }
    __syncthreads();

    const float alpha = alpha_p[0];
    const float gmax = gmaxv[b * ND + lane];
    const float inv  = 1.0f / gsumv[b * ND + lane];

    for (int r = 0; r < K4_ROWS / 4; ++r) {
        const int m = blk * K4_ROWS + r * 4 + wave;
        const size_t ro = ((size_t)b * NM + m) * ND;
        const float a = agg[ro + lane];

        rowA[wave][lane] = a;
        float s = 0.f;
        #pragma unroll
        for (int d = 0; d < ND; ++d)
            s = fmaf(rowA[wave][d], WaT[d * ND + lane], s);

        const float attn = __expf(s - gmax) * inv;
        rowW[wave][lane] = a * attn;
        float nf = 0.f;
        #pragma unroll
        for (int d = 0; d < ND; ++d)
            nf = fmaf(rowW[wave][d], WpT[d * ND + lane], nf);

        out[ro + lane] = alpha * prev[ro + lane] + (1.f - alpha) * nf;
    }
}

extern "C" void kernel_launch(void* const* d_in, const int* in_sizes, int n_in,
                              void* d_out, int out_size, void* d_ws, size_t ws_size,
                              hipStream_t stream) {
    const float* inc     = (const float*)d_in[0];
    const float* ef      = (const float*)d_in[1];
    const float* prev    = (const float*)d_in[2];
    const float* Wa      = (const float*)d_in[3];
    const float* Wp      = (const float*)d_in[4];
    const float* alpha_p = (const float*)d_in[5];
    float* out = (float*)d_out;

    float* agg   = (float*)d_ws;                       // B*M*D floats (16 MB)
    float* pmax  = agg  + (size_t)NB * NM * ND;        // B*256*64 floats
    float* psum  = pmax + (size_t)NB * K1_NBLK * ND;   // B*256*64 floats
    float* gmaxv = psum + (size_t)NB * K1_NBLK * ND;   // B*64
    float* gsumv = gmaxv + NB * ND;                    // B*64

    k1_agg_partial<<<NB * K1_NBLK, 256, 0, stream>>>(inc, ef, Wa, agg, pmax, psum);
    k3_combine<<<NB, 256, 0, stream>>>(pmax, psum, gmaxv, gsumv);
    k4_final<<<NB * K4_NBLK, 256, 0, stream>>>(agg, Wa, Wp, prev, gmaxv, gsumv, alpha_p, out);
}